// Round 1
// baseline (126.771 us; speedup 1.0000x reference)
//
#include <hip/hip_runtime.h>
#include <hip/hip_bf16.h>
#include <math.h>

#define N_ROWS 8192
#define DIM 256          // K
#define NCLS 128
#define INV_T 14.2857142857142857f   // 1/0.07

typedef short bf16x8 __attribute__((ext_vector_type(8)));
typedef float f32x4 __attribute__((ext_vector_type(4)));

#define AS1 __attribute__((address_space(1)))
#define AS3 __attribute__((address_space(3)))

__device__ __forceinline__ void load16_to_lds(const void* g, void* lds) {
  // dest = wave-uniform LDS base + lane*16 (HW rule); gptr is per-lane
  __builtin_amdgcn_global_load_lds((const AS1 void*)g, (AS3 void*)lds, 16, 0, 0);
}

__device__ __forceinline__ unsigned short f2bf(float x) {
  union { __hip_bfloat16 b; unsigned short u; } cv;
  cv.b = __float2bfloat16(x);
  return cv.u;
}

// ---------------- histogram of labels ----------------
__global__ __launch_bounds__(256) void hist_kernel(const int* __restrict__ labels,
                                                   int* __restrict__ counts) {
  int i = blockIdx.x * 256 + threadIdx.x;
  if (i < N_ROWS) atomicAdd(&counts[labels[i]], 1);
}

// ---------------- row-normalize + bf16 convert ----------------
// 4 rows/block (1 wave per row); lane handles 4 consecutive elements.
__global__ __launch_bounds__(256) void normalize_kernel(const float* __restrict__ f,
                                                        unsigned short* __restrict__ fnb) {
  const int row = blockIdx.x * 4 + (threadIdx.x >> 6);
  const int l = threadIdx.x & 63;
  const float4 v = ((const float4*)(f + (size_t)row * DIM))[l];
  float ss = v.x * v.x + v.y * v.y + v.z * v.z + v.w * v.w;
#pragma unroll
  for (int m = 32; m >= 1; m >>= 1) ss += __shfl_xor(ss, m, 64);
  const float inv = 1.0f / fmaxf(sqrtf(ss), 1e-6f);
  ushort4 o;
  o.x = f2bf(v.x * inv);
  o.y = f2bf(v.y * inv);
  o.z = f2bf(v.z * inv);
  o.w = f2bf(v.w * inv);
  ((ushort4*)(fnb + (size_t)row * DIM))[l] = o;
}

// ---------------- fused sim-GEMM + exp/positive reductions ----------------
// Grid (64, 8): blockIdx.x = 128-row tile, blockIdx.y = 1024-col chunk.
// Block 256 threads = 4 waves in 2x2; wave tile 64x64 (4x4 of 16x16x32 MFMA).
// LDS: A full-K tile [128][256] bf16 (64KB) staged once; B [128][32] (8KB) per k-step.
// 16B-chunk XOR swizzle keeps ds_read_b128 at <=2-way bank aliasing (free).
__global__ __launch_bounds__(256, 2) void simloss_main(
    const unsigned short* __restrict__ fnb, const int* __restrict__ labels,
    float* __restrict__ S, float* __restrict__ P) {
  __shared__ __align__(16) unsigned short Atile[128 * 256];  // 64 KB
  __shared__ __align__(16) unsigned short Btile[128 * 32];   // 8 KB

  const int tid = threadIdx.x;
  const int w = tid >> 6;      // wave 0..3
  const int l = tid & 63;      // lane
  const int wr = w >> 1;       // wave row (0..1) -> 64 rows
  const int wc = w & 1;        // wave col (0..1) -> 64 cols
  const int ln15 = l & 15;
  const int q = l >> 4;        // quad 0..3
  const int ibase = blockIdx.x * 128;
  const int ybase = blockIdx.y * 1024;

  // ---- stage A [128][256] bf16, swizzled: chunk16 c of row r stored at c^(r&7)
  {
    const char* gbase = (const char*)fnb;
#pragma unroll
    for (int r = 0; r < 16; ++r) {
      int off = r * 4096 + w * 1024 + l * 16;  // byte offset in Atile
      int row = off >> 9;                      // 512 B per row
      int c = ((off >> 4) & 31) ^ (row & 7);   // source 16B-chunk index
      const char* g = gbase + (size_t)(ibase + row) * 512 + c * 16;
      char* lp = (char*)Atile + r * 4096 + w * 1024;  // wave-uniform base
      load16_to_lds(g, lp);
    }
  }

  // row labels for this block (fixed across j-tiles)
  int rowlab[16];
#pragma unroll
  for (int mi = 0; mi < 4; ++mi)
#pragma unroll
    for (int rg = 0; rg < 4; ++rg)
      rowlab[mi * 4 + rg] = labels[ibase + wr * 64 + mi * 16 + q * 4 + rg];

  float s_acc[16], p_acc[16];
#pragma unroll
  for (int t = 0; t < 16; ++t) { s_acc[t] = 0.f; p_acc[t] = 0.f; }

  for (int jt = 0; jt < 8; ++jt) {
    const int jbase = ybase + jt * 128;
    int labJ[4];
#pragma unroll
    for (int ni = 0; ni < 4; ++ni)
      labJ[ni] = labels[jbase + wc * 64 + ni * 16 + ln15];

    f32x4 acc[4][4];
#pragma unroll
    for (int mi = 0; mi < 4; ++mi)
#pragma unroll
      for (int ni = 0; ni < 4; ++ni) acc[mi][ni] = (f32x4)0.0f;

    for (int kt = 0; kt < 8; ++kt) {
      __syncthreads();  // Btile consumed by previous iteration
      // stage B [128][32] bf16: chunk16 c of row n stored at c^((n>>1)&3)
      {
        const char* gbase = (const char*)fnb;
#pragma unroll
        for (int r = 0; r < 2; ++r) {
          int off = r * 4096 + w * 1024 + l * 16;
          int row = off >> 6;  // 64 B per row
          int c = ((off >> 4) & 3) ^ ((row >> 1) & 3);
          const char* g = gbase + (size_t)(jbase + row) * 512 + kt * 64 + c * 16;
          char* lp = (char*)Btile + r * 4096 + w * 1024;
          load16_to_lds(g, lp);
        }
      }
      __syncthreads();  // staging (A on first pass, B always) complete

      bf16x8 af[4], bf[4];
#pragma unroll
      for (int mi = 0; mi < 4; ++mi) {
        int row = wr * 64 + mi * 16 + ln15;
        int c = (kt * 4 + q) ^ (row & 7);
        af[mi] = *(const bf16x8*)((const char*)Atile + row * 512 + c * 16);
      }
#pragma unroll
      for (int ni = 0; ni < 4; ++ni) {
        int n = wc * 64 + ni * 16 + ln15;
        int c = q ^ ((n >> 1) & 3);
        bf[ni] = *(const bf16x8*)((const char*)Btile + n * 64 + c * 16);
      }
#pragma unroll
      for (int mi = 0; mi < 4; ++mi)
#pragma unroll
        for (int ni = 0; ni < 4; ++ni)
          acc[mi][ni] = __builtin_amdgcn_mfma_f32_16x16x32_bf16(af[mi], bf[ni],
                                                               acc[mi][ni], 0, 0, 0);
    }

    // epilogue: sim -> exp-sum + positive-sim-sum (diagonal contributes exactly
    // e=1, p=10; subtracted in finalize — no per-element diag masking here)
#pragma unroll
    for (int mi = 0; mi < 4; ++mi) {
#pragma unroll
      for (int rg = 0; rg < 4; ++rg) {
        const int t = mi * 4 + rg;
        const int labI = rowlab[t];
        float s_add = 0.f, p_add = 0.f;
#pragma unroll
        for (int ni = 0; ni < 4; ++ni) {
          float x = acc[mi][ni][rg] * INV_T;
          float sim = fminf(10.0f, fmaxf(-10.0f, x));
          s_add += __expf(sim - 10.0f);
          p_add += (labJ[ni] == labI) ? sim : 0.0f;
        }
        s_acc[t] += s_add;
        p_acc[t] += p_add;
      }
    }
  }

  // reduce across the 16 lanes of each quad-group (cols), then atomics
#pragma unroll
  for (int m = 1; m <= 8; m <<= 1) {
#pragma unroll
    for (int t = 0; t < 16; ++t) {
      s_acc[t] += __shfl_xor(s_acc[t], m, 64);
      p_acc[t] += __shfl_xor(p_acc[t], m, 64);
    }
  }
  if (ln15 == 0) {
#pragma unroll
    for (int t = 0; t < 16; ++t) {
      const int row = ibase + wr * 64 + (t >> 2) * 16 + q * 4 + (t & 3);
      atomicAdd(&S[row], s_acc[t]);
      atomicAdd(&P[row], p_acc[t]);
    }
  }
}

// ---------------- finalize: per-row loss + scalar mean ----------------
__global__ __launch_bounds__(1024) void finalize_kernel(
    const float* __restrict__ S, const float* __restrict__ P,
    const int* __restrict__ labels, const int* __restrict__ counts,
    float* __restrict__ out) {
  float lsum = 0.f, vsum = 0.f;
  for (int i = threadIdx.x; i < N_ROWS; i += 1024) {
    const int cnt = counts[labels[i]] - 1;  // positives excluding self
    if (cnt > 0) {
      // subtract exact diagonal contributions (e=1, p=10)
      const float lse = 10.0f + logf(S[i] - 1.0f);
      const float mlp = (P[i] - 10.0f) / (float)cnt - lse;
      lsum += -mlp;  // TEMPERATURE/BASE_TEMPERATURE == 1
      vsum += 1.0f;
    }
  }
#pragma unroll
  for (int m = 32; m >= 1; m >>= 1) {
    lsum += __shfl_xor(lsum, m, 64);
    vsum += __shfl_xor(vsum, m, 64);
  }
  __shared__ float ls[16], vs[16];
  const int wv = threadIdx.x >> 6;
  if ((threadIdx.x & 63) == 0) { ls[wv] = lsum; vs[wv] = vsum; }
  __syncthreads();
  if (threadIdx.x == 0) {
    float L = 0.f, V = 0.f;
    for (int k = 0; k < 16; ++k) { L += ls[k]; V += vs[k]; }
    out[0] = (V > 0.f) ? (L / fmaxf(V, 1.0f)) : 0.f;
  }
}

extern "C" void kernel_launch(void* const* d_in, const int* in_sizes, int n_in,
                              void* d_out, int out_size, void* d_ws, size_t ws_size,
                              hipStream_t stream) {
  const float* feat = (const float*)d_in[0];
  const int* labels = (const int*)d_in[1];
  float* out = (float*)d_out;

  char* ws = (char*)d_ws;
  unsigned short* fnb = (unsigned short*)ws;                 // bf16 [8192][256], 4 MB
  float* S = (float*)(ws + (size_t)N_ROWS * DIM * 2);        // [8192]
  float* P = S + N_ROWS;                                     // [8192]
  int* counts = (int*)(P + N_ROWS);                          // [128]

  // zero accumulators (ws is poisoned before every launch)
  hipMemsetAsync(S, 0, (size_t)(2 * N_ROWS) * sizeof(float) + NCLS * sizeof(int), stream);

  hist_kernel<<<N_ROWS / 256, 256, 0, stream>>>(labels, counts);
  normalize_kernel<<<N_ROWS / 4, 256, 0, stream>>>(feat, fnb);

  dim3 grid(N_ROWS / 128, N_ROWS / 1024);  // (64, 8)
  simloss_main<<<grid, 256, 0, stream>>>(fnb, labels, S, P);

  finalize_kernel<<<1, 1024, 0, stream>>>(S, P, labels, counts, out);
}